// Round 2
// baseline (481.538 us; speedup 1.0000x reference)
//
#include <hip/hip_runtime.h>
#include <hip/hip_bf16.h>

// JointNet: out[b,t,u,:] = tanh(enc@w1a [bt] + dec@w1b [bu] + b1) @ w2 + b2
// B=4 T=256 U=64 D=640 INNER=640 V=1024;  M = B*T*U = 65536
//
// Phase 1: encp[1024][640], decp[256][640] fp32 (decp includes +b1)   (fp32 tiled GEMM)
// Phase 2: w2bT[1024][640] bf16 (transposed so GEMM B-frags are k-contiguous)
// Phase 3: Hb[65536][640] bf16 = tanh(encp[m>>6] + decp[(m>>14)*64 + (m&63)])
// Phase 4: out = Hb @ w2bT^T + b2, m97-structure bf16 MFMA GEMM (128x128xBK32)

typedef __attribute__((ext_vector_type(4))) float  f32x4;
typedef __attribute__((ext_vector_type(8))) __bf16 bf16x8;
typedef __attribute__((ext_vector_type(8))) unsigned short us8;

#define T_DIM 256
#define U_DIM 64
#define D_IN 640
#define INNER 640
#define VOCAB 1024
#define M_TOT 65536   // 4*256*64
#define RE 1024       // B*T rows of encp
#define RD 256        // B*U rows of decp

// ws layout (bytes)
#define ENCP_B (RE * INNER * 4)                 // 2,621,440
#define DECP_B (RD * INNER * 4)                 //   655,360
#define W2BT_B (VOCAB * INNER * 2)              // 1,310,720
#define HB_B   ((size_t)M_TOT * INNER * 2)      // 83,886,080
#define OFF_DECP ((size_t)ENCP_B)
#define OFF_W2BT (OFF_DECP + DECP_B)
#define OFF_HB   (OFF_W2BT + W2BT_B)
#define NEED_FULL (OFF_HB + HB_B)

__device__ __forceinline__ unsigned short f2bf(float f) {
    unsigned int u = __float_as_uint(f);
    u = (u + 0x7FFFu + ((u >> 16) & 1u)) >> 16;   // round-to-nearest-even
    return (unsigned short)u;
}

__device__ __forceinline__ float fast_tanh(float x) {
    // tanh(x) = 1 - 2/(exp2(2*log2e*x)+1); v_exp_f32 + v_rcp_f32
    float e = __builtin_amdgcn_exp2f(x * 2.8853900817779268f);
    return 1.0f - 2.0f * __builtin_amdgcn_rcpf(e + 1.0f);
}

__device__ __forceinline__ void gl_lds16(const void* g, void* l) {
    // async global->LDS, 16B per lane; LDS dest is wave-uniform base + lane*16
    __builtin_amdgcn_global_load_lds(
        (__attribute__((address_space(1))) void*)g,
        (__attribute__((address_space(3))) void*)l, 16, 0, 0);
}

// ---------------- Phase 1: fp32 projection GEMMs ----------------
// grid: 160 blocks enc (16 mt x 10 nt) + 40 blocks dec (4 x 10); 256 thr; 64x64 tile, BK=16
__global__ __launch_bounds__(256) void proj_kernel(
        const float* __restrict__ enc, const float* __restrict__ dec,
        const float* __restrict__ w1, const float* __restrict__ b1,
        float* __restrict__ encp, float* __restrict__ decp) {
    __shared__ __align__(16) float At[16][68];   // A^T tile: [k][row]
    __shared__ __align__(16) float Bt[16][68];   // B tile: [k][n]
    int bx = blockIdx.x;
    const float* Ap; float* Op; const float* Wp; int mt, nt; bool isdec;
    if (bx < 160) { isdec = false; mt = bx / 10; nt = bx % 10; Ap = enc; Op = encp; Wp = w1; }
    else { isdec = true; int i = bx - 160; mt = i / 10; nt = i % 10; Ap = dec; Op = decp; Wp = w1 + 640 * 640; }
    int m0 = mt * 64, n0 = nt * 64;
    int t = threadIdx.x;
    int tx = t & 15, ty = t >> 4;
    int ar = t >> 2, ac = t & 3;     // A loader: row, k-chunk(4)
    int br = t >> 4, bc = t & 15;    // B loader: k-row, col4
    float acc[4][4] = {};
    for (int k0 = 0; k0 < 640; k0 += 16) {
        f32x4 av = *(const f32x4*)&Ap[(m0 + ar) * 640 + k0 + ac * 4];
        f32x4 bv = *(const f32x4*)&Wp[(k0 + br) * 640 + n0 + bc * 4];
        __syncthreads();
        At[ac * 4 + 0][ar] = av[0]; At[ac * 4 + 1][ar] = av[1];
        At[ac * 4 + 2][ar] = av[2]; At[ac * 4 + 3][ar] = av[3];
        *(f32x4*)&Bt[br][bc * 4] = bv;
        __syncthreads();
        #pragma unroll
        for (int kk = 0; kk < 16; ++kk) {
            f32x4 a = *(const f32x4*)&At[kk][ty * 4];
            f32x4 b = *(const f32x4*)&Bt[kk][tx * 4];
            #pragma unroll
            for (int i = 0; i < 4; ++i)
                #pragma unroll
                for (int j = 0; j < 4; ++j)
                    acc[i][j] += a[i] * b[j];
        }
    }
    f32x4 bias = {0.f, 0.f, 0.f, 0.f};
    if (isdec) bias = *(const f32x4*)&b1[n0 + tx * 4];
    #pragma unroll
    for (int i = 0; i < 4; ++i) {
        f32x4 o;
        #pragma unroll
        for (int j = 0; j < 4; ++j) o[j] = acc[i][j] + bias[j];
        *(f32x4*)&Op[(m0 + ty * 4 + i) * 640 + n0 + tx * 4] = o;
    }
}

// ---------------- Phase 2: w2 [640][1024] f32 -> w2bT [1024][640] bf16 ----------------
// grid: 160 blocks (10 kt x 16 nt), 64x64 tiles via LDS transpose
__global__ __launch_bounds__(256) void w2conv_kernel(
        const float* __restrict__ w2, unsigned short* __restrict__ w2bT) {
    __shared__ float tile[64][65];
    int bx = blockIdx.x;
    int kt = bx % 10, nt = bx / 10;
    int k0 = kt * 64, n0 = nt * 64;
    int t = threadIdx.x;
    #pragma unroll
    for (int p = 0; p < 4; ++p) {
        int id = t + p * 256;          // 1024 float4-loads of the 64x64 tile
        int r = id >> 4, c4 = id & 15;
        f32x4 v = *(const f32x4*)&w2[(k0 + r) * 1024 + n0 + c4 * 4];
        tile[r][c4 * 4 + 0] = v[0]; tile[r][c4 * 4 + 1] = v[1];
        tile[r][c4 * 4 + 2] = v[2]; tile[r][c4 * 4 + 3] = v[3];
    }
    __syncthreads();
    #pragma unroll
    for (int p = 0; p < 2; ++p) {
        int id = t + p * 256;          // 512 x 16B stores
        int n = id >> 3, ch = id & 7;
        us8 hv;
        #pragma unroll
        for (int q = 0; q < 8; ++q) hv[q] = f2bf(tile[ch * 8 + q][n]);
        *(us8*)&w2bT[(n0 + n) * 640 + k0 + ch * 8] = hv;
    }
}

// ---------------- Phase 3: Hb = bf16(tanh(encp + decp)) ----------------
// 1 thread = 8 contiguous k of one row m; grid 20480 x 256 exact
__global__ __launch_bounds__(256) void hmat_kernel(
        const float* __restrict__ encp, const float* __restrict__ decp,
        unsigned short* __restrict__ Hb) {
    int c = blockIdx.x * 256 + threadIdx.x;   // 0..5242879
    int m = c / 80;
    int kc = (c - m * 80) * 8;
    int r1 = m >> 6;                           // b*T + t
    int r2 = ((m >> 14) << 6) | (m & 63);      // b*U + u
    const float* ep = encp + r1 * 640 + kc;
    const float* dp = decp + r2 * 640 + kc;
    f32x4 e0 = *(const f32x4*)ep, e1 = *(const f32x4*)(ep + 4);
    f32x4 d0 = *(const f32x4*)dp, d1 = *(const f32x4*)(dp + 4);
    us8 hv;
    #pragma unroll
    for (int q = 0; q < 4; ++q) hv[q] = f2bf(fast_tanh(e0[q] + d0[q]));
    #pragma unroll
    for (int q = 0; q < 4; ++q) hv[4 + q] = f2bf(fast_tanh(e1[q] + d1[q]));
    *(us8*)&Hb[(size_t)m * 640 + kc] = hv;
}

// ---------------- Phase 4: out = Hb @ w2bT^T + b2 ----------------
// m97 structure: BM=BN=128 BK=32, 4 waves each 64x64 (4x4 frags of 16x16x32 bf16)
// FUSED=1 fallback computes the A-tile (tanh) in-kernel instead of reading Hb.
template<int FUSED>
__global__ __launch_bounds__(256) void jgemm_kernel(
        const unsigned short* __restrict__ Hb, const unsigned short* __restrict__ w2bT,
        const float* __restrict__ encp, const float* __restrict__ decp,
        const float* __restrict__ b2, float* __restrict__ out) {
    __shared__ __align__(16) unsigned short As[128 * 32];
    __shared__ __align__(16) unsigned short Bs[128 * 32];
    int bx = blockIdx.x;
    int nt = bx & 7, mt = bx >> 3;
    int m0 = mt << 7, n0 = nt << 7;
    int tid = threadIdx.x;
    int lane = tid & 63, wave = tid >> 6;
    int wr = (wave >> 1) * 64, wc = (wave & 1) * 64;
    f32x4 acc[4][4] = {};
    int fr = lane & 15, fk = (lane >> 4) << 3;

    for (int kt = 0; kt < 20; ++kt) {
        int k0 = kt << 5;
        __syncthreads();   // previous iter's ds_reads done before restage
        if constexpr (!FUSED) {
            #pragma unroll
            for (int j = 0; j < 2; ++j) {
                int srow = wave * 32 + j * 16 + (lane >> 2);
                const char* ag = (const char*)Hb + (size_t)(m0 + srow) * 1280 + k0 * 2 + (lane & 3) * 16;
                const char* bg = (const char*)w2bT + (size_t)(n0 + srow) * 1280 + k0 * 2 + (lane & 3) * 16;
                gl_lds16(ag, (void*)&As[(wave * 32 + j * 16) * 32]);
                gl_lds16(bg, (void*)&Bs[(wave * 32 + j * 16) * 32]);
            }
        } else {
            int row = tid >> 1, kh = tid & 1;
            int m = m0 + row;
            int r1g = m >> 6;
            int r2g = ((m >> 14) << 6) | (m & 63);
            const float* ep = encp + r1g * 640 + k0 + kh * 16;
            const float* dp = decp + r2g * 640 + k0 + kh * 16;
            f32x4 e0 = *(const f32x4*)ep,       e1 = *(const f32x4*)(ep + 4);
            f32x4 e2 = *(const f32x4*)(ep + 8), e3 = *(const f32x4*)(ep + 12);
            f32x4 q0 = *(const f32x4*)dp,       q1 = *(const f32x4*)(dp + 4);
            f32x4 q2 = *(const f32x4*)(dp + 8), q3 = *(const f32x4*)(dp + 12);
            us8 h0, h1;
            #pragma unroll
            for (int q = 0; q < 4; ++q) {
                h0[q]     = f2bf(fast_tanh(e0[q] + q0[q]));
                h0[4 + q] = f2bf(fast_tanh(e1[q] + q1[q]));
                h1[q]     = f2bf(fast_tanh(e2[q] + q2[q]));
                h1[4 + q] = f2bf(fast_tanh(e3[q] + q3[q]));
            }
            *(us8*)&As[row * 32 + kh * 16] = h0;
            *(us8*)&As[row * 32 + kh * 16 + 8] = h1;
            #pragma unroll
            for (int j = 0; j < 2; ++j) {
                int srow = wave * 32 + j * 16 + (lane >> 2);
                const char* bg = (const char*)w2bT + (size_t)(n0 + srow) * 1280 + k0 * 2 + (lane & 3) * 16;
                gl_lds16(bg, (void*)&Bs[(wave * 32 + j * 16) * 32]);
            }
        }
        __syncthreads();   // staging visible
        bf16x8 af[4], bf[4];
        #pragma unroll
        for (int i = 0; i < 4; ++i) {
            af[i] = *(const bf16x8*)&As[(wr + i * 16 + fr) * 32 + fk];
            bf[i] = *(const bf16x8*)&Bs[(wc + i * 16 + fr) * 32 + fk];
        }
        #pragma unroll
        for (int i = 0; i < 4; ++i)
            #pragma unroll
            for (int j = 0; j < 4; ++j)
                acc[i][j] = __builtin_amdgcn_mfma_f32_16x16x32_bf16(af[i], bf[j], acc[i][j], 0, 0, 0);
    }

    // epilogue: C/D layout col=lane&15, row=(lane>>4)*4+reg  [m89/m91-verified]
    int ccol = lane & 15, crow = (lane >> 4) << 2;
    #pragma unroll
    for (int j = 0; j < 4; ++j) {
        int col = n0 + wc + j * 16 + ccol;
        float bb = b2[col];
        #pragma unroll
        for (int i = 0; i < 4; ++i) {
            int row = m0 + wr + i * 16 + crow;
            #pragma unroll
            for (int r = 0; r < 4; ++r)
                out[(size_t)(row + r) * 1024 + col] = acc[i][j][r] + bb;
        }
    }
}

extern "C" void kernel_launch(void* const* d_in, const int* in_sizes, int n_in,
                              void* d_out, int out_size, void* d_ws, size_t ws_size,
                              hipStream_t stream) {
    const float* enc = (const float*)d_in[0];
    const float* dec = (const float*)d_in[1];
    const float* w1  = (const float*)d_in[2];
    const float* b1  = (const float*)d_in[3];
    const float* w2  = (const float*)d_in[4];
    const float* b2  = (const float*)d_in[5];
    float* out = (float*)d_out;

    char* w = (char*)d_ws;
    float* encp = (float*)w;
    float* decp = (float*)(w + OFF_DECP);
    unsigned short* w2bT = (unsigned short*)(w + OFF_W2BT);
    unsigned short* Hb = (unsigned short*)(w + OFF_HB);

    proj_kernel<<<200, 256, 0, stream>>>(enc, dec, w1, b1, encp, decp);
    w2conv_kernel<<<160, 256, 0, stream>>>(w2, w2bT);
    if (ws_size >= NEED_FULL) {
        hmat_kernel<<<20480, 256, 0, stream>>>(encp, decp, Hb);
        jgemm_kernel<0><<<4096, 256, 0, stream>>>(Hb, w2bT, encp, decp, b2, out);
    } else {
        jgemm_kernel<1><<<4096, 256, 0, stream>>>(Hb, w2bT, encp, decp, b2, out);
    }
}

// Round 3
// 462.652 us; speedup vs baseline: 1.0408x; 1.0408x over previous
//
#include <hip/hip_runtime.h>
#include <hip/hip_bf16.h>

// JointNet: out[b,t,u,:] = tanh(enc@w1a [bt] + dec@w1b [bu] + b1) @ w2 + b2
// B=4 T=256 U=64 D=640 INNER=640 V=1024;  M = B*T*U = 65536
//
// prep : encp[1024][640], decp[256][640] fp32 (decp includes +b1)  AND
//        w2bT[1024][640] bf16 (transposed, k-contiguous)           (one kernel)
// hmat : Hb[65536][640] bf16 = tanh(encp[m>>6] + decp[(m>>14)*64 + (m&63)])
// jgemm: out = Hb @ w2bT^T + b2, m97-structure bf16 MFMA GEMM (128x128xBK32)
//        + T1 XCD-chunked block swizzle (all 8 nt of an mt on one XCD)

typedef __attribute__((ext_vector_type(4))) float  f32x4;
typedef __attribute__((ext_vector_type(8))) __bf16 bf16x8;
typedef __attribute__((ext_vector_type(8))) unsigned short us8;

#define INNER 640
#define VOCAB 1024
#define M_TOT 65536   // 4*256*64
#define RE 1024       // B*T rows of encp
#define RD 256        // B*U rows of decp

// ws layout (bytes)
#define ENCP_B (RE * INNER * 4)                 // 2,621,440
#define DECP_B (RD * INNER * 4)                 //   655,360
#define W2BT_B (VOCAB * INNER * 2)              // 1,310,720
#define HB_B   ((size_t)M_TOT * INNER * 2)      // 83,886,080
#define OFF_DECP ((size_t)ENCP_B)
#define OFF_W2BT (OFF_DECP + DECP_B)
#define OFF_HB   (OFF_W2BT + W2BT_B)
#define NEED_FULL (OFF_HB + HB_B)

__device__ __forceinline__ unsigned short f2bf(float f) {
    unsigned int u = __float_as_uint(f);
    u = (u + 0x7FFFu + ((u >> 16) & 1u)) >> 16;   // round-to-nearest-even
    return (unsigned short)u;
}

__device__ __forceinline__ float fast_tanh(float x) {
    // tanh(x) = 1 - 2/(exp2(2*log2e*x)+1); v_exp_f32 + v_rcp_f32
    float e = __builtin_amdgcn_exp2f(x * 2.8853900817779268f);
    return 1.0f - 2.0f * __builtin_amdgcn_rcpf(e + 1.0f);
}

__device__ __forceinline__ void gl_lds16(const void* g, void* l) {
    // async global->LDS, 16B per lane; LDS dest is wave-uniform base + lane*16
    __builtin_amdgcn_global_load_lds(
        (__attribute__((address_space(1))) void*)g,
        (__attribute__((address_space(3))) void*)l, 16, 0, 0);
}

// ---------------- prep: proj GEMMs (blocks 0..199) + w2 transpose/cast (200..359) --------
// proj: 64x64 tile, BK=16, fp32; enc 16x10 tiles, dec 4x10 tiles
// w2conv: 64x64 tiles via LDS transpose, f32 -> bf16
__global__ __launch_bounds__(256) void prep_kernel(
        const float* __restrict__ enc, const float* __restrict__ dec,
        const float* __restrict__ w1, const float* __restrict__ b1,
        const float* __restrict__ w2,
        float* __restrict__ encp, float* __restrict__ decp,
        unsigned short* __restrict__ w2bT) {
    __shared__ __align__(16) char smem[64 * 65 * 4];   // max(proj 8704, w2conv 16640)
    int bx = blockIdx.x;
    int t = threadIdx.x;
    if (bx < 200) {
        float (*At)[68] = (float(*)[68])smem;                    // [16][68]
        float (*Bt)[68] = (float(*)[68])(smem + 16 * 68 * 4);    // [16][68]
        const float* Ap; float* Op; const float* Wp; int mt, nt; bool isdec;
        if (bx < 160) { isdec = false; mt = bx / 10; nt = bx % 10; Ap = enc; Op = encp; Wp = w1; }
        else { isdec = true; int i = bx - 160; mt = i / 10; nt = i % 10; Ap = dec; Op = decp; Wp = w1 + 640 * 640; }
        int m0 = mt * 64, n0 = nt * 64;
        int tx = t & 15, ty = t >> 4;
        int ar = t >> 2, ac = t & 3;     // A loader: row, k-chunk(4)
        int br = t >> 4, bc = t & 15;    // B loader: k-row, col4
        float acc[4][4] = {};
        for (int k0 = 0; k0 < 640; k0 += 16) {
            f32x4 av = *(const f32x4*)&Ap[(m0 + ar) * 640 + k0 + ac * 4];
            f32x4 bv = *(const f32x4*)&Wp[(k0 + br) * 640 + n0 + bc * 4];
            __syncthreads();
            At[ac * 4 + 0][ar] = av[0]; At[ac * 4 + 1][ar] = av[1];
            At[ac * 4 + 2][ar] = av[2]; At[ac * 4 + 3][ar] = av[3];
            *(f32x4*)&Bt[br][bc * 4] = bv;
            __syncthreads();
            #pragma unroll
            for (int kk = 0; kk < 16; ++kk) {
                f32x4 a = *(const f32x4*)&At[kk][ty * 4];
                f32x4 b = *(const f32x4*)&Bt[kk][tx * 4];
                #pragma unroll
                for (int i = 0; i < 4; ++i)
                    #pragma unroll
                    for (int j = 0; j < 4; ++j)
                        acc[i][j] += a[i] * b[j];
            }
        }
        f32x4 bias = {0.f, 0.f, 0.f, 0.f};
        if (isdec) bias = *(const f32x4*)&b1[n0 + tx * 4];
        #pragma unroll
        for (int i = 0; i < 4; ++i) {
            f32x4 o;
            #pragma unroll
            for (int j = 0; j < 4; ++j) o[j] = acc[i][j] + bias[j];
            *(f32x4*)&Op[(m0 + ty * 4 + i) * 640 + n0 + nt * 0 + tx * 4] = o;
        }
    } else {
        float (*tile)[65] = (float(*)[65])smem;                  // [64][65]
        int i = bx - 200;
        int kt = i % 10, ntc = i / 10;
        int k0 = kt * 64, n0 = ntc * 64;
        #pragma unroll
        for (int p = 0; p < 4; ++p) {
            int id = t + p * 256;          // 1024 float4-loads of the 64x64 tile
            int r = id >> 4, c4 = id & 15;
            f32x4 v = *(const f32x4*)&w2[(k0 + r) * 1024 + n0 + c4 * 4];
            tile[r][c4 * 4 + 0] = v[0]; tile[r][c4 * 4 + 1] = v[1];
            tile[r][c4 * 4 + 2] = v[2]; tile[r][c4 * 4 + 3] = v[3];
        }
        __syncthreads();
        #pragma unroll
        for (int p = 0; p < 2; ++p) {
            int id = t + p * 256;          // 512 x 16B stores
            int n = id >> 3, ch = id & 7;
            us8 hv;
            #pragma unroll
            for (int q = 0; q < 8; ++q) hv[q] = f2bf(tile[ch * 8 + q][n]);
            *(us8*)&w2bT[(n0 + n) * 640 + k0 + ch * 8] = hv;
        }
    }
}

// ---------------- hmat: Hb = bf16(tanh(encp + decp)) ----------------
// 1 thread = 8 contiguous k of one row m; grid 20480 x 256 exact
__global__ __launch_bounds__(256) void hmat_kernel(
        const float* __restrict__ encp, const float* __restrict__ decp,
        unsigned short* __restrict__ Hb) {
    int c = blockIdx.x * 256 + threadIdx.x;   // 0..5242879
    int m = c / 80;
    int kc = (c - m * 80) * 8;
    int r1 = m >> 6;                           // b*T + t
    int r2 = ((m >> 14) << 6) | (m & 63);      // b*U + u
    const float* ep = encp + r1 * 640 + kc;
    const float* dp = decp + r2 * 640 + kc;
    f32x4 e0 = *(const f32x4*)ep, e1 = *(const f32x4*)(ep + 4);
    f32x4 d0 = *(const f32x4*)dp, d1 = *(const f32x4*)(dp + 4);
    us8 hv;
    #pragma unroll
    for (int q = 0; q < 4; ++q) hv[q] = f2bf(fast_tanh(e0[q] + d0[q]));
    #pragma unroll
    for (int q = 0; q < 4; ++q) hv[4 + q] = f2bf(fast_tanh(e1[q] + d1[q]));
    *(us8*)&Hb[(size_t)m * 640 + kc] = hv;
}

// ---------------- jgemm: out = Hb @ w2bT^T + b2 ----------------
// m97 structure: BM=BN=128 BK=32, 4 waves each 64x64 (4x4 frags of 16x16x32 bf16)
// T1: XCD-chunked swizzle so all 8 nt column-tiles of one mt run on the same XCD.
// FUSED=1 fallback computes the A-tile (tanh) in-kernel instead of reading Hb.
template<int FUSED>
__global__ __launch_bounds__(256) void jgemm_kernel(
        const unsigned short* __restrict__ Hb, const unsigned short* __restrict__ w2bT,
        const float* __restrict__ encp, const float* __restrict__ decp,
        const float* __restrict__ b2, float* __restrict__ out) {
    __shared__ __align__(16) unsigned short As[128 * 32];
    __shared__ __align__(16) unsigned short Bs[128 * 32];
    int bx = blockIdx.x;
    int lb = ((bx & 7) << 9) | (bx >> 3);   // bijective XCD swizzle (4096 % 8 == 0)
    int nt = lb & 7, mt = lb >> 3;
    int m0 = mt << 7, n0 = nt << 7;
    int tid = threadIdx.x;
    int lane = tid & 63, wave = tid >> 6;
    int wr = (wave >> 1) * 64, wc = (wave & 1) * 64;
    f32x4 acc[4][4] = {};
    int fr = lane & 15, fk = (lane >> 4) << 3;

    for (int kt = 0; kt < 20; ++kt) {
        int k0 = kt << 5;
        __syncthreads();   // previous iter's ds_reads done before restage
        if constexpr (!FUSED) {
            #pragma unroll
            for (int j = 0; j < 2; ++j) {
                int srow = wave * 32 + j * 16 + (lane >> 2);
                const char* ag = (const char*)Hb + (size_t)(m0 + srow) * 1280 + k0 * 2 + (lane & 3) * 16;
                const char* bg = (const char*)w2bT + (size_t)(n0 + srow) * 1280 + k0 * 2 + (lane & 3) * 16;
                gl_lds16(ag, (void*)&As[(wave * 32 + j * 16) * 32]);
                gl_lds16(bg, (void*)&Bs[(wave * 32 + j * 16) * 32]);
            }
        } else {
            int row = tid >> 1, kh = tid & 1;
            int m = m0 + row;
            int r1g = m >> 6;
            int r2g = ((m >> 14) << 6) | (m & 63);
            const float* ep = encp + r1g * 640 + k0 + kh * 16;
            const float* dp = decp + r2g * 640 + k0 + kh * 16;
            f32x4 e0 = *(const f32x4*)ep,       e1 = *(const f32x4*)(ep + 4);
            f32x4 e2 = *(const f32x4*)(ep + 8), e3 = *(const f32x4*)(ep + 12);
            f32x4 q0 = *(const f32x4*)dp,       q1 = *(const f32x4*)(dp + 4);
            f32x4 q2 = *(const f32x4*)(dp + 8), q3 = *(const f32x4*)(dp + 12);
            us8 h0, h1;
            #pragma unroll
            for (int q = 0; q < 4; ++q) {
                h0[q]     = f2bf(fast_tanh(e0[q] + q0[q]));
                h0[4 + q] = f2bf(fast_tanh(e1[q] + q1[q]));
                h1[q]     = f2bf(fast_tanh(e2[q] + q2[q]));
                h1[4 + q] = f2bf(fast_tanh(e3[q] + q3[q]));
            }
            *(us8*)&As[row * 32 + kh * 16] = h0;
            *(us8*)&As[row * 32 + kh * 16 + 8] = h1;
            #pragma unroll
            for (int j = 0; j < 2; ++j) {
                int srow = wave * 32 + j * 16 + (lane >> 2);
                const char* bg = (const char*)w2bT + (size_t)(n0 + srow) * 1280 + k0 * 2 + (lane & 3) * 16;
                gl_lds16(bg, (void*)&Bs[(wave * 32 + j * 16) * 32]);
            }
        }
        __syncthreads();   // staging visible
        bf16x8 af[4], bf[4];
        #pragma unroll
        for (int i = 0; i < 4; ++i) {
            af[i] = *(const bf16x8*)&As[(wr + i * 16 + fr) * 32 + fk];
            bf[i] = *(const bf16x8*)&Bs[(wc + i * 16 + fr) * 32 + fk];
        }
        #pragma unroll
        for (int i = 0; i < 4; ++i)
            #pragma unroll
            for (int j = 0; j < 4; ++j)
                acc[i][j] = __builtin_amdgcn_mfma_f32_16x16x32_bf16(af[i], bf[j], acc[i][j], 0, 0, 0);
    }

    // epilogue: C/D layout col=lane&15, row=(lane>>4)*4+reg  [m89/m91-verified]
    int ccol = lane & 15, crow = (lane >> 4) << 2;
    #pragma unroll
    for (int j = 0; j < 4; ++j) {
        int col = n0 + wc + j * 16 + ccol;
        float bb = b2[col];
        #pragma unroll
        for (int i = 0; i < 4; ++i) {
            int row = m0 + wr + i * 16 + crow;
            #pragma unroll
            for (int r = 0; r < 4; ++r)
                out[(size_t)(row + r) * 1024 + col] = acc[i][j][r] + bb;
        }
    }
}

extern "C" void kernel_launch(void* const* d_in, const int* in_sizes, int n_in,
                              void* d_out, int out_size, void* d_ws, size_t ws_size,
                              hipStream_t stream) {
    const float* enc = (const float*)d_in[0];
    const float* dec = (const float*)d_in[1];
    const float* w1  = (const float*)d_in[2];
    const float* b1  = (const float*)d_in[3];
    const float* w2  = (const float*)d_in[4];
    const float* b2  = (const float*)d_in[5];
    float* out = (float*)d_out;

    char* w = (char*)d_ws;
    float* encp = (float*)w;
    float* decp = (float*)(w + OFF_DECP);
    unsigned short* w2bT = (unsigned short*)(w + OFF_W2BT);
    unsigned short* Hb = (unsigned short*)(w + OFF_HB);

    prep_kernel<<<360, 256, 0, stream>>>(enc, dec, w1, b1, w2, encp, decp, w2bT);
    if (ws_size >= NEED_FULL) {
        hmat_kernel<<<20480, 256, 0, stream>>>(encp, decp, Hb);
        jgemm_kernel<0><<<4096, 256, 0, stream>>>(Hb, w2bT, encp, decp, b2, out);
    } else {
        jgemm_kernel<1><<<4096, 256, 0, stream>>>(Hb, w2bT, encp, decp, b2, out);
    }
}

// Round 4
// 457.567 us; speedup vs baseline: 1.0524x; 1.0111x over previous
//
#include <hip/hip_runtime.h>
#include <hip/hip_bf16.h>

// JointNet: out[b,t,u,:] = tanh(enc@w1a [bt] + dec@w1b [bu] + b1) @ w2 + b2
// B=4 T=256 U=64 D=640 INNER=640 V=1024;  M = B*T*U = 65536
//
// prep    : encp/decp fp32 proj (+b1 in decp) AND w2bT bf16 transpose (one kernel)
// hmat    : Hb[65536][640] bf16 = tanh(encp[m>>6] + decp[(m>>14)*64|(m&63)])
// jgemm256: out = Hb @ w2bT^T + b2 -- 256x256 tile, BK=32, 8 waves, 4-deep
//           LDS pipeline with counted vmcnt (never 0 in-loop), 1 barrier/K-tile.
//           Race invariant: stage for tile t+3 (issued after barrier B_t) writes
//           buf (t+3)&3 == (t-1)&3, whose last reads completed before B_t; the
//           writes are fenced by the vmcnt at B_{t+3}.

typedef __attribute__((ext_vector_type(4))) float  f32x4;
typedef __attribute__((ext_vector_type(8))) __bf16 bf16x8;
typedef __attribute__((ext_vector_type(8))) unsigned short us8;

#define INNER 640
#define VOCAB 1024
#define M_TOT 65536   // 4*256*64
#define RE 1024       // B*T rows of encp
#define RD 256        // B*U rows of decp

// ws layout (bytes)
#define ENCP_B (RE * INNER * 4)                 // 2,621,440
#define DECP_B (RD * INNER * 4)                 //   655,360
#define W2BT_B (VOCAB * INNER * 2)              // 1,310,720
#define HB_B   ((size_t)M_TOT * INNER * 2)      // 83,886,080
#define OFF_DECP ((size_t)ENCP_B)
#define OFF_W2BT (OFF_DECP + DECP_B)
#define OFF_HB   (OFF_W2BT + W2BT_B)
#define NEED_FULL (OFF_HB + HB_B)

__device__ __forceinline__ unsigned short f2bf(float f) {
    unsigned int u = __float_as_uint(f);
    u = (u + 0x7FFFu + ((u >> 16) & 1u)) >> 16;   // round-to-nearest-even
    return (unsigned short)u;
}

__device__ __forceinline__ float fast_tanh(float x) {
    float e = __builtin_amdgcn_exp2f(x * 2.8853900817779268f);
    return 1.0f - 2.0f * __builtin_amdgcn_rcpf(e + 1.0f);
}

__device__ __forceinline__ void gl_lds16(const void* g, void* l) {
    // async global->LDS, 16B per lane; LDS dest is wave-uniform base + lane*16
    __builtin_amdgcn_global_load_lds(
        (__attribute__((address_space(1))) void*)g,
        (__attribute__((address_space(3))) void*)l, 16, 0, 0);
}

// ---------------- prep: proj GEMMs (blocks 0..199) + w2 transpose/cast (200..359) --------
__global__ __launch_bounds__(256) void prep_kernel(
        const float* __restrict__ enc, const float* __restrict__ dec,
        const float* __restrict__ w1, const float* __restrict__ b1,
        const float* __restrict__ w2,
        float* __restrict__ encp, float* __restrict__ decp,
        unsigned short* __restrict__ w2bT) {
    __shared__ __align__(16) char smem[64 * 65 * 4];
    int bx = blockIdx.x;
    int t = threadIdx.x;
    if (bx < 200) {
        float (*At)[68] = (float(*)[68])smem;
        float (*Bt)[68] = (float(*)[68])(smem + 16 * 68 * 4);
        const float* Ap; float* Op; const float* Wp; int mt, nt; bool isdec;
        if (bx < 160) { isdec = false; mt = bx / 10; nt = bx % 10; Ap = enc; Op = encp; Wp = w1; }
        else { isdec = true; int i = bx - 160; mt = i / 10; nt = i % 10; Ap = dec; Op = decp; Wp = w1 + 640 * 640; }
        int m0 = mt * 64, n0 = nt * 64;
        int tx = t & 15, ty = t >> 4;
        int ar = t >> 2, ac = t & 3;
        int br = t >> 4, bc = t & 15;
        float acc[4][4] = {};
        for (int k0 = 0; k0 < 640; k0 += 16) {
            f32x4 av = *(const f32x4*)&Ap[(m0 + ar) * 640 + k0 + ac * 4];
            f32x4 bv = *(const f32x4*)&Wp[(k0 + br) * 640 + n0 + bc * 4];
            __syncthreads();
            At[ac * 4 + 0][ar] = av[0]; At[ac * 4 + 1][ar] = av[1];
            At[ac * 4 + 2][ar] = av[2]; At[ac * 4 + 3][ar] = av[3];
            *(f32x4*)&Bt[br][bc * 4] = bv;
            __syncthreads();
            #pragma unroll
            for (int kk = 0; kk < 16; ++kk) {
                f32x4 a = *(const f32x4*)&At[kk][ty * 4];
                f32x4 b = *(const f32x4*)&Bt[kk][tx * 4];
                #pragma unroll
                for (int i = 0; i < 4; ++i)
                    #pragma unroll
                    for (int j = 0; j < 4; ++j)
                        acc[i][j] += a[i] * b[j];
            }
        }
        f32x4 bias = {0.f, 0.f, 0.f, 0.f};
        if (isdec) bias = *(const f32x4*)&b1[n0 + tx * 4];
        #pragma unroll
        for (int i = 0; i < 4; ++i) {
            f32x4 o;
            #pragma unroll
            for (int j = 0; j < 4; ++j) o[j] = acc[i][j] + bias[j];
            *(f32x4*)&Op[(m0 + ty * 4 + i) * 640 + n0 + tx * 4] = o;
        }
    } else {
        float (*tile)[65] = (float(*)[65])smem;
        int i = bx - 200;
        int kt = i % 10, ntc = i / 10;
        int k0 = kt * 64, n0 = ntc * 64;
        #pragma unroll
        for (int p = 0; p < 4; ++p) {
            int id = t + p * 256;
            int r = id >> 4, c4 = id & 15;
            f32x4 v = *(const f32x4*)&w2[(k0 + r) * 1024 + n0 + c4 * 4];
            tile[r][c4 * 4 + 0] = v[0]; tile[r][c4 * 4 + 1] = v[1];
            tile[r][c4 * 4 + 2] = v[2]; tile[r][c4 * 4 + 3] = v[3];
        }
        __syncthreads();
        #pragma unroll
        for (int p = 0; p < 2; ++p) {
            int id = t + p * 256;
            int n = id >> 3, ch = id & 7;
            us8 hv;
            #pragma unroll
            for (int q = 0; q < 8; ++q) hv[q] = f2bf(tile[ch * 8 + q][n]);
            *(us8*)&w2bT[(n0 + n) * 640 + k0 + ch * 8] = hv;
        }
    }
}

// ---------------- hmat: Hb = bf16(tanh(encp + decp)) ----------------
__global__ __launch_bounds__(256) void hmat_kernel(
        const float* __restrict__ encp, const float* __restrict__ decp,
        unsigned short* __restrict__ Hb) {
    int c = blockIdx.x * 256 + threadIdx.x;
    int m = c / 80;
    int kc = (c - m * 80) * 8;
    int r1 = m >> 6;
    int r2 = ((m >> 14) << 6) | (m & 63);
    const float* ep = encp + r1 * 640 + kc;
    const float* dp = decp + r2 * 640 + kc;
    f32x4 e0 = *(const f32x4*)ep, e1 = *(const f32x4*)(ep + 4);
    f32x4 d0 = *(const f32x4*)dp, d1 = *(const f32x4*)(dp + 4);
    us8 hv;
    #pragma unroll
    for (int q = 0; q < 4; ++q) hv[q] = f2bf(fast_tanh(e0[q] + d0[q]));
    #pragma unroll
    for (int q = 0; q < 4; ++q) hv[4 + q] = f2bf(fast_tanh(e1[q] + d1[q]));
    *(us8*)&Hb[(size_t)m * 640 + kc] = hv;
}

// ---------------- jgemm256: 256x256 tile, BK=32, 4-deep counted-vmcnt pipeline --------
// Per K-tile t: vmcnt(8) [tiles t+1,t+2 in flight] -> s_barrier -> stage tile t+3
// -> 12 ds_read_b128 frags -> setprio(1) 32 MFMA setprio(0).
// LDS [256][32] bf16 rows = 64 B: frag b128 reads are bank-balanced (8 lanes/quad
// = LDS BW floor), no swizzle needed; staging stays linear for global_load_lds.
__global__ __launch_bounds__(512, 2) void jgemm256_kernel(
        const unsigned short* __restrict__ Hb, const unsigned short* __restrict__ w2bT,
        const float* __restrict__ b2, float* __restrict__ out) {
    __shared__ __align__(16) unsigned short sA[4][256 * 32];
    __shared__ __align__(16) unsigned short sB[4][256 * 32];
    int bx = blockIdx.x;
    int lb = ((bx & 7) << 7) | (bx >> 3);   // XCD-chunked bijective swizzle (1024 % 8 == 0)
    int nt = lb & 3, mt = lb >> 2;
    int m0 = mt << 8, n0 = nt << 8;
    int tid = threadIdx.x;
    int lane = tid & 63, wave = tid >> 6;
    int wm = wave >> 2, wn = wave & 3;

    // staging: per tile, A = 1024 x 16B chunks; thread tid loads chunks tid and 512+tid
    // chunk c -> row c>>2, kchunk c&3;  q=1 adds 128 rows = 163840 global bytes
    const char* HbBase = (const char*)Hb + (size_t)(m0 + (tid >> 2)) * 1280 + (tid & 3) * 16;
    const char* WbBase = (const char*)w2bT + (size_t)(n0 + (tid >> 2)) * 1280 + (tid & 3) * 16;

    f32x4 acc[8][4] = {};
    int fr = lane & 15, fk8 = (lane >> 4) << 3;
    int arow0 = (wm << 7) + fr;   // + ri*16
    int brow0 = (wn << 6) + fr;   // + ci*16

#define STAGE_TILE(tt) do { \
    unsigned short* As_ = sA[(tt) & 3]; unsigned short* Bs_ = sB[(tt) & 3]; \
    const char* ga_ = HbBase + (tt) * 64; \
    const char* gb_ = WbBase + (tt) * 64; \
    gl_lds16(ga_,          (void*)(As_ + wave * 512)); \
    gl_lds16(ga_ + 163840, (void*)(As_ + 4096 + wave * 512)); \
    gl_lds16(gb_,          (void*)(Bs_ + wave * 512)); \
    gl_lds16(gb_ + 163840, (void*)(Bs_ + 4096 + wave * 512)); \
} while (0)

#define JTILE(t_, VN_, DOST_) do { \
    asm volatile("s_waitcnt vmcnt(%0)" :: "i"(VN_) : "memory"); \
    __builtin_amdgcn_s_barrier(); \
    __builtin_amdgcn_sched_barrier(0); \
    if (DOST_) STAGE_TILE((t_) + 3); \
    const unsigned short* As_r = sA[(t_) & 3]; \
    const unsigned short* Bs_r = sB[(t_) & 3]; \
    bf16x8 af[8], bfv[4]; \
    _Pragma("unroll") for (int ri = 0; ri < 8; ++ri) \
        af[ri] = *(const bf16x8*)&As_r[(arow0 + ri * 16) * 32 + fk8]; \
    _Pragma("unroll") for (int ci = 0; ci < 4; ++ci) \
        bfv[ci] = *(const bf16x8*)&Bs_r[(brow0 + ci * 16) * 32 + fk8]; \
    __builtin_amdgcn_s_setprio(1); \
    _Pragma("unroll") for (int ri = 0; ri < 8; ++ri) \
        _Pragma("unroll") for (int ci = 0; ci < 4; ++ci) \
            acc[ri][ci] = __builtin_amdgcn_mfma_f32_16x16x32_bf16(af[ri], bfv[ci], acc[ri][ci], 0, 0, 0); \
    __builtin_amdgcn_s_setprio(0); \
} while (0)

    STAGE_TILE(0); STAGE_TILE(1); STAGE_TILE(2);
    for (int t = 0; t < 17; ++t) {
        JTILE(t, 8, true);          // stages t+3 (<= 19)
    }
    JTILE(17, 8, false);
    JTILE(18, 4, false);
    JTILE(19, 0, false);

#undef JTILE
#undef STAGE_TILE

    // epilogue: C/D layout col=lane&15, row=(lane>>4)*4+reg  [m89/m91-verified]
    int crow = (lane >> 4) << 2;
    #pragma unroll
    for (int ci = 0; ci < 4; ++ci) {
        int col = n0 + (wn << 6) + ci * 16 + fr;
        float bb = b2[col];
        #pragma unroll
        for (int ri = 0; ri < 8; ++ri) {
            int row = m0 + (wm << 7) + ri * 16 + crow;
            #pragma unroll
            for (int r = 0; r < 4; ++r)
                out[(size_t)(row + r) * 1024 + col] = acc[ri][ci][r] + bb;
        }
    }
}

// ---------------- fallback (small ws): old 128x128 fused kernel ----------------
__global__ __launch_bounds__(256) void jgemm_fused_kernel(
        const unsigned short* __restrict__ w2bT,
        const float* __restrict__ encp, const float* __restrict__ decp,
        const float* __restrict__ b2, float* __restrict__ out) {
    __shared__ __align__(16) unsigned short As[128 * 32];
    __shared__ __align__(16) unsigned short Bs[128 * 32];
    int bx = blockIdx.x;
    int lb = ((bx & 7) << 9) | (bx >> 3);
    int nt = lb & 7, mt = lb >> 3;
    int m0 = mt << 7, n0 = nt << 7;
    int tid = threadIdx.x;
    int lane = tid & 63, wave = tid >> 6;
    int wr = (wave >> 1) * 64, wc = (wave & 1) * 64;
    f32x4 acc[4][4] = {};
    int fr = lane & 15, fk = (lane >> 4) << 3;
    for (int kt = 0; kt < 20; ++kt) {
        int k0 = kt << 5;
        __syncthreads();
        int row = tid >> 1, kh = tid & 1;
        int m = m0 + row;
        int r1g = m >> 6;
        int r2g = ((m >> 14) << 6) | (m & 63);
        const float* ep = encp + r1g * 640 + k0 + kh * 16;
        const float* dp = decp + r2g * 640 + k0 + kh * 16;
        f32x4 e0 = *(const f32x4*)ep,       e1 = *(const f32x4*)(ep + 4);
        f32x4 e2 = *(const f32x4*)(ep + 8), e3 = *(const f32x4*)(ep + 12);
        f32x4 q0 = *(const f32x4*)dp,       q1 = *(const f32x4*)(dp + 4);
        f32x4 q2 = *(const f32x4*)(dp + 8), q3 = *(const f32x4*)(dp + 12);
        us8 h0, h1;
        #pragma unroll
        for (int q = 0; q < 4; ++q) {
            h0[q]     = f2bf(fast_tanh(e0[q] + q0[q]));
            h0[4 + q] = f2bf(fast_tanh(e1[q] + q1[q]));
            h1[q]     = f2bf(fast_tanh(e2[q] + q2[q]));
            h1[4 + q] = f2bf(fast_tanh(e3[q] + q3[q]));
        }
        *(us8*)&As[row * 32 + kh * 16] = h0;
        *(us8*)&As[row * 32 + kh * 16 + 8] = h1;
        #pragma unroll
        for (int j = 0; j < 2; ++j) {
            int srow = wave * 32 + j * 16 + (lane >> 2);
            const char* bg = (const char*)w2bT + (size_t)(n0 + srow) * 1280 + k0 * 2 + (lane & 3) * 16;
            gl_lds16(bg, (void*)&Bs[(wave * 32 + j * 16) * 32]);
        }
        __syncthreads();
        bf16x8 af[4], bf[4];
        #pragma unroll
        for (int i = 0; i < 4; ++i) {
            af[i] = *(const bf16x8*)&As[(wr + i * 16 + fr) * 32 + fk];
            bf[i] = *(const bf16x8*)&Bs[(wc + i * 16 + fr) * 32 + fk];
        }
        #pragma unroll
        for (int i = 0; i < 4; ++i)
            #pragma unroll
            for (int j = 0; j < 4; ++j)
                acc[i][j] = __builtin_amdgcn_mfma_f32_16x16x32_bf16(af[i], bf[j], acc[i][j], 0, 0, 0);
    }
    int ccol = lane & 15, crow = (lane >> 4) << 2;
    #pragma unroll
    for (int j = 0; j < 4; ++j) {
        int col = n0 + wc + j * 16 + ccol;
        float bb = b2[col];
        #pragma unroll
        for (int i = 0; i < 4; ++i) {
            int row = m0 + wr + i * 16 + crow;
            #pragma unroll
            for (int r = 0; r < 4; ++r)
                out[(size_t)(row + r) * 1024 + col] = acc[i][j][r] + bb;
        }
    }
}

extern "C" void kernel_launch(void* const* d_in, const int* in_sizes, int n_in,
                              void* d_out, int out_size, void* d_ws, size_t ws_size,
                              hipStream_t stream) {
    const float* enc = (const float*)d_in[0];
    const float* dec = (const float*)d_in[1];
    const float* w1  = (const float*)d_in[2];
    const float* b1  = (const float*)d_in[3];
    const float* w2  = (const float*)d_in[4];
    const float* b2  = (const float*)d_in[5];
    float* out = (float*)d_out;

    char* w = (char*)d_ws;
    float* encp = (float*)w;
    float* decp = (float*)(w + OFF_DECP);
    unsigned short* w2bT = (unsigned short*)(w + OFF_W2BT);
    unsigned short* Hb = (unsigned short*)(w + OFF_HB);

    prep_kernel<<<360, 256, 0, stream>>>(enc, dec, w1, b1, w2, encp, decp, w2bT);
    if (ws_size >= NEED_FULL) {
        hmat_kernel<<<20480, 256, 0, stream>>>(encp, decp, Hb);
        jgemm256_kernel<<<1024, 512, 0, stream>>>(Hb, w2bT, b2, out);
    } else {
        jgemm_fused_kernel<<<4096, 256, 0, stream>>>(w2bT, encp, decp, b2, out);
    }
}